// Round 1
// baseline (118.557 us; speedup 1.0000x reference)
//
#include <hip/hip_runtime.h>
#include <hip/hip_bf16.h>
#include <hip/hip_fp16.h>

#define PP 9216   // 96*96 pixels per batch
#define OO 384    // qkv channels

typedef _Float16 f16x8 __attribute__((ext_vector_type(8)));
typedef _Float16 h2    __attribute__((ext_vector_type(2)));
typedef float    f32x4 __attribute__((ext_vector_type(4)));

#if defined(__has_builtin)
# if __has_builtin(__builtin_amdgcn_fdot2)
#  define HAS_FDOT2 1
# endif
#endif

__device__ __forceinline__ float dot2acc(h2 a, h2 b, float c) {
#ifdef HAS_FDOT2
    return __builtin_amdgcn_fdot2(a, b, c, false);
#else
    return c + (float)a[0] * (float)b[0] + (float)a[1] * (float)b[1];
#endif
}

__device__ __forceinline__ f16x8 cvt8(float4 u0, float4 u1) {
    f16x8 r;
    r[0] = (_Float16)u0.x; r[1] = (_Float16)u0.y;
    r[2] = (_Float16)u0.z; r[3] = (_Float16)u0.w;
    r[4] = (_Float16)u1.x; r[5] = (_Float16)u1.y;
    r[6] = (_Float16)u1.z; r[7] = (_Float16)u1.w;
    return r;
}

// ---------------------------------------------------------------------------
// QKV GEMM, fused f32->f16 conversion (no prep / no xT round-trip).
// qkv[b][p][o] = sum_c x[b][c][p] * w[o][c].
// A (pixels) loaded as 8 per-channel coalesced f32 loads + cvt (RTN, same
// rounding as the old prep). B (weights) loaded f32 + cvt, L2-hot.
// Block: 64px x 192o. Wave: 32px x 96o. LDS epilogue for coalesced stores.
// ---------------------------------------------------------------------------
__global__ __launch_bounds__(256) void qkv_gemm(
    const float* __restrict__ x, const float* __restrict__ wq,
    const float* __restrict__ wk, const float* __restrict__ wv,
    _Float16* __restrict__ qkv)
{
    __shared__ _Float16 sEpi[4][32][104];   // per-wave 32px x 96o strip (pad 104)

    const int b = blockIdx.z;
    const int p0 = blockIdx.x * 64;
    const int nbase = blockIdx.y * 192;
    const int t = threadIdx.x;
    const int w = t >> 6, lane = t & 63;
    const int lm = lane & 15, quad = lane >> 4;
    const int ms0 = (w & 1) * 32;
    const int nw = (w >> 1) * 96;

    const float* xb = x + (size_t)b * 128 * PP;
    _Float16* qb = qkv + (size_t)b * PP * OO;

    // A fragments: pixel p0+ms0+ms*16+lm, channels kc*32+quad*8+j
    f16x8 A[2][4];
    #pragma unroll
    for (int ms = 0; ms < 2; ms++) {
        const float* xp = xb + p0 + ms0 + ms * 16 + lm;
        #pragma unroll
        for (int kc = 0; kc < 4; kc++) {
            const float* s = xp + (size_t)(kc * 32 + quad * 8) * PP;
            float tmp[8];
            #pragma unroll
            for (int j = 0; j < 8; j++) tmp[j] = s[(size_t)j * PP];
            #pragma unroll
            for (int j = 0; j < 8; j++) A[ms][kc][j] = (_Float16)tmp[j];
        }
    }

    for (int nt = 0; nt < 6; nt++) {
        const int n0 = nbase + nw + nt * 16;
        const int o = n0 + lm;
        const float* wrow = (o < 128) ? (wq + (size_t)o * 128)
                          : (o < 256) ? (wk + (size_t)(o - 128) * 128)
                                      : (wv + (size_t)(o - 256) * 128);
        f16x8 Bf[4];
        #pragma unroll
        for (int kc = 0; kc < 4; kc++) {
            float4 u0 = *(const float4*)(wrow + kc * 32 + quad * 8);
            float4 u1 = *(const float4*)(wrow + kc * 32 + quad * 8 + 4);
            Bf[kc] = cvt8(u0, u1);
        }
        f32x4 acc[2];
        #pragma unroll
        for (int ms = 0; ms < 2; ms++) {
            acc[ms] = (f32x4){0.f, 0.f, 0.f, 0.f};
            #pragma unroll
            for (int kc = 0; kc < 4; kc++)
                acc[ms] = __builtin_amdgcn_mfma_f32_16x16x32_f16(A[ms][kc], Bf[kc], acc[ms], 0, 0, 0);
        }
        #pragma unroll
        for (int ms = 0; ms < 2; ms++)
            #pragma unroll
            for (int r = 0; r < 4; r++)
                sEpi[w][ms * 16 + quad * 4 + r][nt * 16 + lm] = (_Float16)acc[ms][r];
    }

    // per-wave epilogue: 32 rows x 96 halfs (192B contiguous per row)
    #pragma unroll
    for (int it = 0; it < 6; it++) {
        int idx = it * 64 + lane;      // 0..383
        int row = idx / 12;            // 0..31
        int ch  = idx % 12;            // 16B chunk within row
        uint4 v = *(const uint4*)&sEpi[w][row][ch * 8];
        *(uint4*)(qb + (size_t)(p0 + ms0 + row) * OO + nbase + nw + ch * 8) = v;
    }
}

// ---------------------------------------------------------------------------
// Windowed attention. qkv[b][p][384] f16 (q:0-127,k:128-255,v:256-383,
// each h*32+d). One block per (8x8 tile, b, h). ao[b][p][128] f16.
// sS stride 27 (odd) -> conflict-free; softmax spread over all 4 waves.
// ---------------------------------------------------------------------------
__global__ __launch_bounds__(256) void attn2(
    const _Float16* __restrict__ qkv, _Float16* __restrict__ ao)
{
    __shared__ _Float16 sK[144 * 40];
    __shared__ _Float16 sV[144 * 40];
    __shared__ float sS[64 * 27];

    const int t = threadIdx.x;
    const int x0 = blockIdx.x * 8, y0 = blockIdx.y * 8;
    const int b = blockIdx.z >> 2, h = blockIdx.z & 3;
    const _Float16* base = qkv + (size_t)b * PP * OO;

    // stage K,V halo: 144 pos x 32 halfs each, contiguous 64B rows
    for (int u = t; u < 288; u += 256) {
        const int arr = (u >= 144) ? 1 : 0;
        const int pos = u - 144 * arr;
        const int gy = y0 - 2 + pos / 12;
        const int gx = x0 - 2 + pos % 12;
        _Float16* dst = (arr ? sV : sK) + pos * 40;
        if ((unsigned)gy < 96u && (unsigned)gx < 96u) {
            const _Float16* src = base + (size_t)(gy * 96 + gx) * OO + 128 + arr * 128 + h * 32;
            #pragma unroll
            for (int j = 0; j < 4; j++)
                *(uint4*)(dst + j * 8) = *(const uint4*)(src + j * 8);
        } else {
            uint4 z = {0u, 0u, 0u, 0u};
            #pragma unroll
            for (int j = 0; j < 4; j++) *(uint4*)(dst + j * 8) = z;
        }
    }

    const int px = t & 63, w = t >> 6;
    const int ly = px >> 3, lx = px & 7;
    const int gp = (y0 + ly) * 96 + x0 + lx;

    // Q into registers (16 x half2)
    h2 qreg[16];
    {
        const _Float16* qs = base + (size_t)gp * OO + h * 32;
        #pragma unroll
        for (int j = 0; j < 4; j++)
            *(uint4*)(&qreg[j * 4]) = *(const uint4*)(qs + j * 8);
    }
    __syncthreads();

    // scores: wave w handles pos = w, w+4, ...
    const float scale = 0.17677669529663689f;
    for (int pos = w; pos < 25; pos += 4) {
        const int hp = (ly + pos / 5) * 12 + lx + pos % 5;
        const _Float16* kr = sK + hp * 40;
        h2 kreg[16];
        #pragma unroll
        for (int j = 0; j < 4; j++)
            *(uint4*)(&kreg[j * 4]) = *(const uint4*)(kr + j * 8);
        float s0 = 0.f, s1 = 0.f;
        #pragma unroll
        for (int j = 0; j < 8; j++) {
            s0 = dot2acc(qreg[2 * j], kreg[2 * j], s0);
            s1 = dot2acc(qreg[2 * j + 1], kreg[2 * j + 1], s1);
        }
        sS[px * 27 + pos] = (s0 + s1) * scale;
    }
    __syncthreads();

    // softmax over 25 positions: each wave handles 16 pixels in lanes 0-15
    if ((t & 63) < 16) {
        const int sp = (t >> 6) * 16 + (t & 15);
        float* row = sS + sp * 27;
        float m = row[0];
        #pragma unroll
        for (int p = 1; p < 25; p++) m = fmaxf(m, row[p]);
        float sum = 0.f;
        float e[25];
        #pragma unroll
        for (int p = 0; p < 25; p++) { e[p] = __expf(row[p] - m); sum += e[p]; }
        const float inv = 1.f / sum;
        #pragma unroll
        for (int p = 0; p < 25; p++) row[p] = e[p] * inv;
    }
    __syncthreads();

    // PV: wave w handles d in [w*8, w*8+8)
    float at[25];
    #pragma unroll
    for (int p = 0; p < 25; p++) at[p] = sS[px * 27 + p];

    float f[8];
    #pragma unroll
    for (int j = 0; j < 8; j++) f[j] = 0.f;
    for (int p = 0; p < 25; p++) {
        const int hp = (ly + p / 5) * 12 + lx + p % 5;
        h2 vreg[4];
        *(uint4*)vreg = *(const uint4*)(sV + hp * 40 + w * 8);
        #pragma unroll
        for (int j = 0; j < 4; j++) {
            f[2 * j]     += at[p] * (float)vreg[j][0];
            f[2 * j + 1] += at[p] * (float)vreg[j][1];
        }
    }
    _Float16 ho[8];
    #pragma unroll
    for (int j = 0; j < 8; j++) ho[j] = (_Float16)f[j];
    *(uint4*)(ao + ((size_t)b * PP + gp) * 128 + h * 32 + w * 8) = *(uint4*)ho;
}

// ---------------------------------------------------------------------------
// Proj GEMM: out[b][c][p] = sum_o wproj[c][o] * ao[b][p][o], fp32 out.
// Weights f32 -> f16 in-register. Wave tile 16px x 64c (2.25 waves/SIMD).
// Block: 32px x 128c. Grid (288,1,2).
// ---------------------------------------------------------------------------
__global__ __launch_bounds__(256) void proj_gemm(
    const _Float16* __restrict__ ao, const float* __restrict__ wp,
    float* __restrict__ out)
{
    const int b = blockIdx.z;
    const int p0 = blockIdx.x * 32;
    const int t = threadIdx.x;
    const int w = t >> 6, lane = t & 63;
    const int lm = lane & 15, quad = lane >> 4;
    const int ms0 = (w & 1) * 16;
    const int nw = (w >> 1) * 64;

    const _Float16* ab = ao + (size_t)b * PP * 128;
    float* ob = out + (size_t)b * 128 * PP;

    f16x8 A[4];
    #pragma unroll
    for (int kc = 0; kc < 4; kc++)
        A[kc] = *(const f16x8*)(ab + (size_t)(p0 + ms0 + lm) * 128 + kc * 32 + quad * 8);

    #pragma unroll
    for (int nt = 0; nt < 4; nt++) {
        const int n0 = nw + nt * 16;
        const float* wrow = wp + (size_t)(n0 + lm) * 128;
        f16x8 Bf[4];
        #pragma unroll
        for (int kc = 0; kc < 4; kc++) {
            float4 u0 = *(const float4*)(wrow + kc * 32 + quad * 8);
            float4 u1 = *(const float4*)(wrow + kc * 32 + quad * 8 + 4);
            Bf[kc] = cvt8(u0, u1);
        }
        f32x4 acc = (f32x4){0.f, 0.f, 0.f, 0.f};
        #pragma unroll
        for (int kc = 0; kc < 4; kc++)
            acc = __builtin_amdgcn_mfma_f32_16x16x32_f16(A[kc], Bf[kc], acc, 0, 0, 0);
        float4 v = make_float4(acc[0], acc[1], acc[2], acc[3]);
        *(float4*)(ob + (size_t)(n0 + lm) * PP + p0 + ms0 + quad * 4) = v;
    }
}

extern "C" void kernel_launch(void* const* d_in, const int* in_sizes, int n_in,
                              void* d_out, int out_size, void* d_ws, size_t ws_size,
                              hipStream_t stream)
{
    const float* x  = (const float*)d_in[0];
    const float* wq = (const float*)d_in[1];
    const float* wk = (const float*)d_in[2];
    const float* wv = (const float*)d_in[3];
    const float* wp = (const float*)d_in[4];
    float* out = (float*)d_out;

    _Float16* qkvh = (_Float16*)d_ws;            // 2*9216*384
    _Float16* aoh  = qkvh + 7077888;             // 2*9216*128

    qkv_gemm<<<dim3(144, 2, 2), 256, 0, stream>>>(x, wq, wk, wv, qkvh);
    attn2<<<dim3(12, 12, 8), 256, 0, stream>>>(qkvh, aoh);
    proj_gemm<<<dim3(288, 1, 2), 256, 0, stream>>>(aoh, wp, out);
}